// Round 3
// baseline (1278.437 us; speedup 1.0000x reference)
//
#include <hip/hip_runtime.h>
#include <math.h>

#define H 128

typedef float f32x4 __attribute__((ext_vector_type(4)));
typedef __bf16 bf16x8 __attribute__((ext_vector_type(8)));

__device__ __forceinline__ float fast_tanh(float v) {
    // tanh(v) = 1 - 2/(exp(2v)+1); exact at +-inf saturation
    float e = __expf(2.0f * v);
    float r = __builtin_amdgcn_rcpf(e + 1.0f);
    return fmaf(-2.0f, r, 1.0f);
}

// Fully fused: s = tanh(x@w1+b1)@w2 (b2 dropped -- cancels exactly in softmax),
// then UNNORMALIZED softmax pooling: out[g] += exp(s_i)*x_i, denom[g] += exp(s_i).
// Valid since w_i = exp(s-m)/sum == exp(s)/sum and |s| <= sum|w2| ~ 6 (fp32-safe).
// x is read ONCE (registers already hold it as bf16 hi+lo, exact to 2^-16).
//
// R2 lesson: 2 M-tiles/wave kept 64 VGPRs of A-fragments live through the whole
// pooling phase -> needed >128 regs at the (512,2) cap -> 740 MB spill traffic.
// R3: ONE M-tile (16 rows) per wave. A-frags = 32 VGPRs; static need ~90 -> no
// spills. MFMA work per row unchanged; LDS B-reads double (LDS is idle anyway).
__global__ __launch_bounds__(512, 2) void k_fused(
    const float* __restrict__ x, const int* __restrict__ batch,
    const float* __restrict__ w1, const float* __restrict__ b1,
    const float* __restrict__ w2, float* __restrict__ out,
    float* __restrict__ denom, int n, int ntiles)
{
    __shared__ __bf16 wsm[2 * H * H];  // [hi|lo][n][k swizzled] = 64 KB exactly

    const int tid = threadIdx.x;

    // ---- stage w1 (k-major [k][n]) -> LDS transposed [n][k], bf16 hi/lo ----
    for (int idx = tid; idx < H * H; idx += 512) {
        int k = idx >> 7, nn = idx & 127;      // w1[k][nn], coalesced in nn
        float v = w1[idx];
        __bf16 h = (__bf16)v;
        __bf16 l = (__bf16)(v - (float)h);
        int c = (k >> 3) ^ (nn & 15);          // 16B-chunk XOR swizzle
        int pos = nn * H + c * 8 + (k & 7);
        wsm[pos] = h;
        wsm[H * H + pos] = l;
    }

    const int wv = tid >> 6;       // wave 0..7
    const int lane = tid & 63;
    const int p = lane & 15;       // A: m-row / B: n-col / D: col
    const int q = lane >> 4;       // A,B: k-group / D: row-group

    // batch dtype sniff: sorted int64 ends with a zero high word at int32
    // index 2(n-1)+1; here tested via batch[n-1]==0 (low word of elem (n-1)/2
    // for i64 is 0 only in the high-word slot) -- same heuristic as prior rounds.
    const bool is64 = (batch[n - 1] == 0);

    __syncthreads();  // weights ready; read-only below -> no more barriers

    for (int tile = blockIdx.x; tile < ntiles; tile += (int)gridDim.x) {
        const long long base = (long long)tile * 128 + wv * 16;

        // ---- load 1 M-tile of x direct from global, split to bf16 hi/lo ----
        // lane (p,q) holds row base+p, cols kc*32 + q*8 + j
        bf16x8 ah[4], al[4];
        const long long r0 = base + p;
        const bool ok = (r0 < (long long)n);
        {
            const float4* rp = (const float4*)(x + r0 * H);
            #pragma unroll
            for (int kc = 0; kc < 4; ++kc) {
                float4 u0 = {0.f, 0.f, 0.f, 0.f}, u1 = {0.f, 0.f, 0.f, 0.f};
                if (ok) { u0 = rp[kc * 8 + q * 2]; u1 = rp[kc * 8 + q * 2 + 1]; }
                float vals[8] = {u0.x, u0.y, u0.z, u0.w, u1.x, u1.y, u1.z, u1.w};
                #pragma unroll
                for (int j = 0; j < 8; ++j) {
                    __bf16 h = (__bf16)vals[j];
                    ah[kc][j] = h;
                    al[kc][j] = (__bf16)(vals[j] - (float)h);
                }
            }
        }

        // ---- per-nt MFMA + immediate epilogue fold (acc regs reused) ----
        float part[4] = {0.f, 0.f, 0.f, 0.f};

        #pragma unroll
        for (int nt = 0; nt < 8; ++nt) {
            const int nn = nt * 16 + p;
            f32x4 acc = {0.f, 0.f, 0.f, 0.f};
            #pragma unroll
            for (int kc = 0; kc < 4; ++kc) {
                const int c = (kc * 4 + q) ^ p;  // undo swizzle (nn&15 == p)
                const __bf16* bb = &wsm[nn * H + c * 8];
                bf16x8 bh = *(const bf16x8*)bb;
                bf16x8 bl = *(const bf16x8*)(bb + H * H);
                acc = __builtin_amdgcn_mfma_f32_16x16x32_bf16(ah[kc], bh, acc, 0, 0, 0);
                acc = __builtin_amdgcn_mfma_f32_16x16x32_bf16(al[kc], bh, acc, 0, 0, 0);
                acc = __builtin_amdgcn_mfma_f32_16x16x32_bf16(ah[kc], bl, acc, 0, 0, 0);
            }
            const float b1v = b1[nn];
            const float w2v = w2[nn];
            #pragma unroll
            for (int rg = 0; rg < 4; ++rg)
                part[rg] = fmaf(fast_tanh(acc[rg] + b1v), w2v, part[rg]);
        }

        // ---- reduce over 16 col-lanes: each p-group gets full s for its rows ----
        #pragma unroll
        for (int off = 1; off < 16; off <<= 1) {
            #pragma unroll
            for (int rg = 0; rg < 4; ++rg)
                part[rg] += __shfl_xor(part[rg], off);
        }

        // ---- redistribute: lane (p,q) takes s for row base+p ----
        // s(row q*4+rg) is replicated across p-group q; this lane's row p sits
        // in group q_src = p>>2, register rg = p&3. srcl = q_src*16 (p=0 lane).
        float e;
        {
            const int srcl = (p >> 2) * 16;
            float a0 = __shfl(part[0], srcl);
            float a1 = __shfl(part[1], srcl);
            float a2 = __shfl(part[2], srcl);
            float a3 = __shfl(part[3], srcl);
            int rs = p & 3;
            float sv = (rs == 0) ? a0 : (rs == 1) ? a1 : (rs == 2) ? a2 : a3;
            e = ok ? __expf(sv) : 0.0f;
        }

        // ---- graph id for this lane's row ----
        int ga = ok ? (is64 ? batch[(size_t)r0 * 2] : batch[r0]) : 0x7FFFFFFF;

        // ---- segmented pooling over distinct graphs in these 16 rows ----
        // (batch sorted -> typically 1, sometimes 2 iterations)
        while (true) {
            int gm = ga;
            #pragma unroll
            for (int off = 1; off < 16; off <<= 1)
                gm = min(gm, __shfl_xor(gm, off));
            if (gm == 0x7FFFFFFF) break;

            float ea = (ga == gm) ? e : 0.0f;

            // denom partial: sum over the 16 rows (within one p-group)
            float dsum = ea;
            #pragma unroll
            for (int off = 1; off < 16; off <<= 1)
                dsum += __shfl_xor(dsum, off);
            if (lane == 0) atomicAdd(&denom[gm], dsum);

            // weighted x: lane holds cols kc*32+q*8+j of row p; reduce over p
            #pragma unroll
            for (int kc = 0; kc < 4; ++kc) {
                float t[8];
                #pragma unroll
                for (int j = 0; j < 8; ++j)
                    t[j] = ea * ((float)ah[kc][j] + (float)al[kc][j]);
                #pragma unroll
                for (int off = 1; off < 16; off <<= 1) {
                    #pragma unroll
                    for (int j = 0; j < 8; ++j)
                        t[j] += __shfl_xor(t[j], off);
                }
                if (p == 0) {
                    float* ob = out + (size_t)gm * H + kc * 32 + q * 8;
                    #pragma unroll
                    for (int j = 0; j < 8; ++j)
                        atomicAdd(&ob[j], t[j]);
                }
            }

            if (ga == gm) ga = 0x7FFFFFFF;
        }
    }
}

// zero the atomic accumulators (out + denom) -- must run every iteration
__global__ void k_zero(float* __restrict__ out, float* __restrict__ denom,
                       int nf, int g_count)
{
    int i = blockIdx.x * blockDim.x + threadIdx.x;
    if (i < nf) out[i] = 0.0f;
    else if (i < nf + g_count) denom[i - nf] = 0.0f;
}

// out[g,:] /= denom[g]  (denom>0 guard matches reference; empty graphs stay 0)
__global__ void k_norm(float* __restrict__ out, const float* __restrict__ denom,
                       int total4)
{
    int i = blockIdx.x * blockDim.x + threadIdx.x;
    if (i >= total4) return;
    int g = i >> 5;  // 32 float4 per H=128 row
    float d = denom[g];
    float inv = (d > 0.0f) ? (1.0f / d) : 1.0f;
    float4 v = ((float4*)out)[i];
    v.x *= inv; v.y *= inv; v.z *= inv; v.w *= inv;
    ((float4*)out)[i] = v;
}

extern "C" void kernel_launch(void* const* d_in, const int* in_sizes, int n_in,
                              void* d_out, int out_size, void* d_ws, size_t ws_size,
                              hipStream_t stream)
{
    const float* x     = (const float*)d_in[0];
    const int*   batch = (const int*)d_in[1];
    const float* w1    = (const float*)d_in[2];
    const float* b1    = (const float*)d_in[3];
    const float* w2    = (const float*)d_in[4];
    // b2 unused: constant bias cancels exactly in softmax weights
    const int n = in_sizes[0] / H;       // 1e6 rows
    const int G = out_size / H;          // 4096 graphs
    float* out = (float*)d_out;

    float* denom = (float*)d_ws;         // G floats

    const int nf = G * H;
    const int tiles = (n + 127) / 128;   // 128 rows per block tile now
    k_zero<<<(nf + G + 255) / 256, 256, 0, stream>>>(out, denom, nf, G);
    k_fused<<<1024, 512, 0, stream>>>(x, batch, w1, b1, w2, out, denom, n, tiles);
    k_norm<<<(G * 32 + 255) / 256, 256, 0, stream>>>(out, denom, G * 32);
}